// Round 5
// baseline (462.327 us; speedup 1.0000x reference)
//
#include <hip/hip_runtime.h>
#include <hip/hip_bf16.h>

#define B_ 16
#define N_ 2048
#define D_ 64

typedef __bf16 bf16x8 __attribute__((ext_vector_type(8)));
typedef __bf16 bf16x4 __attribute__((ext_vector_type(4)));
typedef __bf16 bf16x2 __attribute__((ext_vector_type(2)));
typedef float  f32x4  __attribute__((ext_vector_type(4)));
typedef float  f32x16 __attribute__((ext_vector_type(16)));

// load 8 bf16 from an 8B-aligned LDS address (two b64 reads)
static __device__ __forceinline__ bf16x8 ld_frag(const __bf16* p) {
  bf16x4 lo = *(const bf16x4*)p;
  bf16x4 hi = *(const bf16x4*)(p + 4);
  return __builtin_shufflevector(lo, hi, 0, 1, 2, 3, 4, 5, 6, 7);
}

// convert 16 staged floats -> bf16 frag layout [kchunk][row][8]
static __device__ __forceinline__ void stage_K(__bf16* dst, int n, int c4,
                                               const f32x4* f) {
  bf16x8 w0, w1;
#pragma unroll
  for (int i = 0; i < 4; ++i) {
    w0[i] = (__bf16)f[0][i]; w0[i + 4] = (__bf16)f[1][i];
    w1[i] = (__bf16)f[2][i]; w1[i + 4] = (__bf16)f[3][i];
  }
  *(bf16x8*)&dst[(2 * c4 + 0) * 512 + n * 8] = w0;
  *(bf16x8*)&dst[(2 * c4 + 1) * 512 + n * 8] = w1;
}

// V^T staging: v[0],v[1] = rows 2g,2g+1 ; v[2],v[3] = rows 2g+32,2g+33
static __device__ __forceinline__ void stage_V(__bf16* dst, int g, int n0,
                                               const f32x4* v) {
#pragma unroll
  for (int p = 0; p < 2; ++p) {
    const int k = 2 * g + 32 * p;
#pragma unroll
    for (int i = 0; i < 4; ++i) {
      bf16x2 pr;
      pr[0] = (__bf16)v[2 * p][i];
      pr[1] = (__bf16)v[2 * p + 1][i];
      *(bf16x2*)&dst[(n0 + i) * 68 + k] = pr;
    }
  }
}

// stage one 64x64 Q tile (pre-scaled by 1/sqrt(D)=0.125) into a frag slab
static __device__ __forceinline__ void stage_Q(__bf16* dst, const float* Qt,
                                               int m, int c4q) {
  const f32x4* src = (const f32x4*)(Qt + (size_t)m * D_ + c4q * 16);
  f32x4 f0 = src[0], f1 = src[1], f2 = src[2], f3 = src[3];
  bf16x8 w0, w1;
#pragma unroll
  for (int i = 0; i < 4; ++i) {
    w0[i]     = (__bf16)(f0[i] * 0.125f);
    w0[i + 4] = (__bf16)(f1[i] * 0.125f);
    w1[i]     = (__bf16)(f2[i] * 0.125f);
    w1[i + 4] = (__bf16)(f3[i] * 0.125f);
  }
  *(bf16x8*)&dst[(2 * c4q + 0) * 512 + m * 8] = w0;
  *(bf16x8*)&dst[(2 * c4q + 1) * 512 + m * 8] = w1;
}

static __device__ __forceinline__ void load_qf(const __bf16* Qs, int wr, int ln,
                                               int half, bf16x8* qf) {
#pragma unroll
  for (int kk = 0; kk < 4; ++kk)
    qf[kk] = *(const bf16x8*)&Qs[(2 * kk + half) * 512 + (32 * wr + ln) * 8];
}

static __device__ __forceinline__ void loadK16(const float* p, f32x4* kp) {
  const f32x4* kq = (const f32x4*)p;
  kp[0] = kq[0]; kp[1] = kq[1]; kp[2] = kq[2]; kp[3] = kq[3];
}
static __device__ __forceinline__ void loadV16(const float* p, f32x4* vp) {
  vp[0] = *(const f32x4*)(p);
  vp[1] = *(const f32x4*)(p + D_);
  vp[2] = *(const f32x4*)(p + 32 * D_);
  vp[3] = *(const f32x4*)(p + 33 * D_);
}

static __device__ __forceinline__ void load_linv(const float* lsum, int wr,
                                                 int half, float* linv) {
#pragma unroll
  for (int r = 0; r < 16; ++r) {
    const int ro = (r & 3) + 8 * (r >> 2) + 4 * half;
    linv[r] = 1.0f / lsum[32 * wr + ro];
  }
}

// pass A over column tiles [0, rowT] of row tile rowT; atomicAdd rowsums -> lsum
static __device__ __forceinline__ void run_passA(
    const float* Kst, int n_st, int c4, __bf16 (*KsL)[4096],
    const bf16x8* qf, float* lsum, int rowT,
    int wr, int wc, int ln, int half) {
  f32x4 kp[4];
  loadK16(Kst, kp);
  stage_K(KsL[0], n_st, c4, kp);
  float sums[16];
#pragma unroll
  for (int r = 0; r < 16; ++r) sums[r] = 0.0f;
  __syncthreads();
#pragma unroll 1
  for (int ct = 0; ct <= rowT; ++ct) {
    const int cur = ct & 1;
    if (ct < rowT) loadK16(Kst + (size_t)(ct + 1) * 64 * D_, kp);
    f32x16 s;
#pragma unroll
    for (int i = 0; i < 16; ++i) s[i] = 0.0f;
#pragma unroll
    for (int kk = 0; kk < 4; ++kk) {
      bf16x8 kf = *(const bf16x8*)&KsL[cur][(2 * kk + half) * 512 + (32 * wc + ln) * 8];
      s = __builtin_amdgcn_mfma_f32_32x32x16_bf16(qf[kk], kf, s, 0, 0, 0);
    }
    const bool diag = (ct == rowT);
#pragma unroll
    for (int r = 0; r < 16; ++r) {
      float e = __expf(s[r]);
      if (diag) {
        const int ro = (r & 3) + 8 * (r >> 2) + 4 * half;
        e = ((32 * wc + ln) <= (32 * wr + ro)) ? e : 0.0f;
      }
      sums[r] += e;
    }
    if (ct < rowT) stage_K(KsL[cur ^ 1], n_st, c4, kp);
    __syncthreads();
  }
#pragma unroll
  for (int r = 0; r < 16; ++r) {
    float v = sums[r];
    v += __shfl_xor(v, 1);
    v += __shfl_xor(v, 2);
    v += __shfl_xor(v, 4);
    v += __shfl_xor(v, 8);
    v += __shfl_xor(v, 16);
    sums[r] = v;
  }
  if (ln == 0) {
#pragma unroll
    for (int r = 0; r < 16; ++r) {
      const int ro = (r & 3) + 8 * (r >> 2) + 4 * half;
      atomicAdd(&lsum[32 * wr + ro], sums[r]);
    }
  }
}

// pass B over column tiles [clo, chi] of row tile at row0T; diag at ct==diagCt
static __device__ __forceinline__ void run_passB(
    const float* Kst, const float* Vst, int n_st, int c4, int gV, int n0v,
    __bf16 (*KsL)[4096], __bf16 (*VtL)[4352], __bf16* Pt,
    const bf16x8* qf, const float* linv, float* Ab, int row0T, int diagCt,
    int clo, int chi, int wr, int wc, int ln, int half,
    f32x16& o0, f32x16& o1) {
  f32x4 kp[4], vp[4];
  loadK16(Kst + (size_t)clo * 64 * D_, kp);
  loadV16(Vst + (size_t)clo * 64 * D_, vp);
  stage_K(KsL[0], n_st, c4, kp);
  stage_V(VtL[0], gV, n0v, vp);
  __syncthreads();
#pragma unroll 1
  for (int ct = clo; ct <= chi; ++ct) {
    const int cur = (ct - clo) & 1;
    const int c0  = ct * 64;
    if (ct < chi) {
      const size_t off = (size_t)(ct + 1) * 64 * D_;
      loadK16(Kst + off, kp);
      loadV16(Vst + off, vp);
    }
    f32x16 s;
#pragma unroll
    for (int i = 0; i < 16; ++i) s[i] = 0.0f;
#pragma unroll
    for (int kk = 0; kk < 4; ++kk) {
      bf16x8 kf = *(const bf16x8*)&KsL[cur][(2 * kk + half) * 512 + (32 * wc + ln) * 8];
      s = __builtin_amdgcn_mfma_f32_32x32x16_bf16(qf[kk], kf, s, 0, 0, 0);
    }
    const bool diag = (ct == diagCt);
#pragma unroll
    for (int r = 0; r < 16; ++r) {
      const int ro = (r & 3) + 8 * (r >> 2) + 4 * half;
      float e = __expf(s[r]);
      if (diag) e = ((32 * wc + ln) <= (32 * wr + ro)) ? e : 0.0f;
      const float pv = e * linv[r];
      __builtin_nontemporal_store(pv,
          Ab + (size_t)(row0T + 32 * wr + ro) * N_ + c0 + 32 * wc + ln);
      Pt[ro * 36 + ln] = (__bf16)pv;   // wave-private: no barrier needed
    }
#pragma unroll
    for (int kk2 = 0; kk2 < 2; ++kk2) {
      bf16x8 af = ld_frag(&Pt[ln * 36 + 16 * kk2 + 8 * half]);
      bf16x8 b0 = ld_frag(&VtL[cur][ln * 68 + 32 * wc + 16 * kk2 + 8 * half]);
      bf16x8 b1 = ld_frag(&VtL[cur][(32 + ln) * 68 + 32 * wc + 16 * kk2 + 8 * half]);
      o0 = __builtin_amdgcn_mfma_f32_32x32x16_bf16(af, b0, o0, 0, 0, 0);
      o1 = __builtin_amdgcn_mfma_f32_32x32x16_bf16(af, b1, o1, 0, 0, 0);
    }
    if (ct < chi) {
      stage_K(KsL[cur ^ 1], n_st, c4, kp);
      stage_V(VtL[cur ^ 1], gV, n0v, vp);
    }
    __syncthreads();
  }
}

// cross-wave reduce (wc=1 -> wc=0) then one HW f32 atomic per element.
// Ored overlays KsL (dead between phases). <=2 atomic addends per O elem
// across the block pair => order-independent => bitwise deterministic.
static __device__ __forceinline__ void reduce_O_atomic(
    float* Ored, float* Ob, int row0T, int wr, int wc, int ln, int half,
    const f32x16& o0, const f32x16& o1) {
  if (wc == 1) {
#pragma unroll
    for (int r = 0; r < 16; ++r) {
      const int ro = (r & 3) + 8 * (r >> 2) + 4 * half;
      Ored[(32 * wr + ro) * 64 + ln]      = o0[r];
      Ored[(32 * wr + ro) * 64 + 32 + ln] = o1[r];
    }
  }
  __syncthreads();
  if (wc == 0) {
#pragma unroll
    for (int r = 0; r < 16; ++r) {
      const int ro = (r & 3) + 8 * (r >> 2) + 4 * half;
      float* op = Ob + (size_t)(row0T + 32 * wr + ro) * D_;
      unsafeAtomicAdd(op + ln,      o0[r] + Ored[(32 * wr + ro) * 64 + ln]);
      unsafeAtomicAdd(op + 32 + ln, o1[r] + Ored[(32 * wr + ro) * 64 + 32 + ln]);
    }
  }
  __syncthreads();
}

__global__ __launch_bounds__(256, 2)
void General_Attention_62251255988379_kernel(const float* __restrict__ Q,
                                             const float* __restrict__ K,
                                             const float* __restrict__ V,
                                             float* __restrict__ out) {
  __shared__ __bf16 QsL[2][4096];       // [0]: heavy Q tile, [1]: light (X only)
  __shared__ __bf16 KsL[2][4096];       // double-buffered K tile (frag layout)
  __shared__ __bf16 VtL[2][4352];       // double-buffered V^T [d][k], stride 68
  __shared__ __bf16 PtW[4 * 32 * 36];   // per-wave P slab
  __shared__ float  lsumH[64], lsumL[64];

  const int tid  = threadIdx.x;
  const int blk  = blockIdx.x;
  const int bb   = blk & 15;
  const int u    = blk >> 4;
  const bool isX = (u < 16);            // X dispatches first (heavier chain)
  const int up   = isX ? u : (u - 16);  // pair id: blocks c and c+256 share up
  const int rH   = 31 - up;             // heavy row tile
  const int rL   = up;                  // light row tile
  const int x    = 15 - up;             // X: heavy cols [0,x) ; Y: [x, rH]
  const int row0H = rH * 64, row0L = rL * 64;
  const int lane = tid & 63;
  const int wave = tid >> 6;
  const int wr   = wave & 1;
  const int wc   = wave >> 1;
  const int ln   = lane & 31;
  const int half = lane >> 5;

  const float* Qb = Q + (size_t)bb * N_ * D_;
  const float* Kb = K + (size_t)bb * N_ * D_;
  const float* Vb = V + (size_t)bb * N_ * D_;
  float* Ob = out + (size_t)bb * N_ * D_;
  float* Ab = out + (size_t)B_ * N_ * D_ + (size_t)bb * N_ * N_;

  if (tid < 64) { lsumH[tid] = 0.0f; lsumL[tid] = 0.0f; }

  // ---- stage Q tiles (heavy always; light for X) ----
  {
    const int m = tid >> 2, c4q = tid & 3;
    stage_Q(QsL[0], Qb + (size_t)row0H * D_, m, c4q);
    if (isX) stage_Q(QsL[1], Qb + (size_t)row0L * D_, m, c4q);
  }
  __syncthreads();

  const int n_st = tid >> 2;
  const int c4   = tid & 3;
  const float* Kst = Kb + (size_t)n_st * D_ + c4 * 16;
  const int gV  = tid >> 4;
  const int n0v = (tid & 15) * 4;
  const float* Vst = Vb + (size_t)(2 * gV) * D_ + n0v;

  bf16x8 qf[4];

  // ===================== pass A =====================
  if (isX) {
    if (x > 0) {  // heavy sums needed only if X writes heavy columns
      load_qf(QsL[0], wr, ln, half, qf);
      run_passA(Kst, n_st, c4, KsL, qf, lsumH, rH, wr, wc, ln, half);
    }
    load_qf(QsL[1], wr, ln, half, qf);
    run_passA(Kst, n_st, c4, KsL, qf, lsumL, rL, wr, wc, ln, half);
  } else {
    load_qf(QsL[0], wr, ln, half, qf);
    run_passA(Kst, n_st, c4, KsL, qf, lsumH, rH, wr, wc, ln, half);
  }
  __syncthreads();   // lsum atomicAdds visible to all waves

  // ===================== pass B =====================
  f32x16 o0, o1;
#pragma unroll
  for (int i = 0; i < 16; ++i) { o0[i] = 0.0f; o1[i] = 0.0f; }
  __bf16* Pt = &PtW[wave * 32 * 36];
  float* Ored = (float*)&KsL[0][0];   // 16 KB scratch overlaying KsL
  float linv[16];

  if (isX) {
    // light tile: all columns [0, rL]
    load_linv(lsumL, wr, half, linv);
    load_qf(QsL[1], wr, ln, half, qf);
    run_passB(Kst, Vst, n_st, c4, gV, n0v, KsL, VtL, Pt, qf, linv,
              Ab, row0L, rL, 0, rL, wr, wc, ln, half, o0, o1);
    reduce_O_atomic(Ored, Ob, row0L, wr, wc, ln, half, o0, o1);
    if (x > 0) {
      // heavy tile: columns [0, x-1] (never includes diag: x <= 15 < rH)
#pragma unroll
      for (int i = 0; i < 16; ++i) { o0[i] = 0.0f; o1[i] = 0.0f; }
      load_linv(lsumH, wr, half, linv);
      load_qf(QsL[0], wr, ln, half, qf);
      run_passB(Kst, Vst, n_st, c4, gV, n0v, KsL, VtL, Pt, qf, linv,
                Ab, row0H, -1, 0, x - 1, wr, wc, ln, half, o0, o1);
      reduce_O_atomic(Ored, Ob, row0H, wr, wc, ln, half, o0, o1);
    }
  } else {
    // heavy tile: columns [x, rH] (includes diag at rH)
    load_linv(lsumH, wr, half, linv);
    load_qf(QsL[0], wr, ln, half, qf);
    run_passB(Kst, Vst, n_st, c4, gV, n0v, KsL, VtL, Pt, qf, linv,
              Ab, row0H, rH, x, rH, wr, wc, ln, half, o0, o1);
    reduce_O_atomic(Ored, Ob, row0H, wr, wc, ln, half, o0, o1);
  }

  // ---- zero-fill strictly-upper att columns: constant 254 KB per block ----
  // X fills rows 0..31, Y rows 32..63 of both tiles' upper regions.
  const int rf0 = isX ? 0 : 32;
  f32x4 z = {0.0f, 0.0f, 0.0f, 0.0f};
  const int cL0 = 64 * (rL + 1);        // light upper region (always nonempty)
#pragma unroll 1
  for (int rr = rf0 + (tid >> 6); rr < rf0 + 32; rr += 4) {
    float* rowp = Ab + (size_t)(row0L + rr) * N_;
    for (int xc = cL0 + (tid & 63) * 4; xc < N_; xc += 256)
      __builtin_nontemporal_store(z, (f32x4*)(rowp + xc));
  }
  const int cH0 = 64 * (rH + 1);        // heavy upper region (empty when up==0)
  if (cH0 < N_) {
#pragma unroll 1
    for (int rr = rf0 + (tid >> 6); rr < rf0 + 32; rr += 4) {
      float* rowp = Ab + (size_t)(row0H + rr) * N_;
      for (int xc = cH0 + (tid & 63) * 4; xc < N_; xc += 256)
        __builtin_nontemporal_store(z, (f32x4*)(rowp + xc));
    }
  }
}

extern "C" void kernel_launch(void* const* d_in, const int* in_sizes, int n_in,
                              void* d_out, int out_size, void* d_ws, size_t ws_size,
                              hipStream_t stream) {
  const float* Q = (const float*)d_in[0];
  const float* K = (const float*)d_in[1];
  const float* V = (const float*)d_in[2];
  (void)in_sizes; (void)n_in; (void)out_size; (void)d_ws; (void)ws_size;
  float* out = (float*)d_out;
  // O region accumulated via <=2 HW f32 atomics per element: must start zeroed
  hipMemsetAsync(d_out, 0, (size_t)B_ * N_ * D_ * sizeof(float), stream);
  General_Attention_62251255988379_kernel<<<dim3(512), dim3(256), 0, stream>>>(Q, K, V, out);
}